// Round 6
// baseline (225.762 us; speedup 1.0000x reference)
//
#include <hip/hip_runtime.h>

// VectorQuantizer on MI355X (gfx950), fp32 — bit-mimics the numpy fp32 reference.
// Round 5: LDS pipe was the limit (16 ds_read_b128/j = 192cyc vs 128cyc FMA ->
// VALUBusy 72%). Process 2 pixels/thread so each codebook ds_read feeds two FMA
// chains: LDS 192cyc < VALU 256cyc per j -> VALU-bound, and the two independent
// sequential chains give ILP=2, enough for one wave to saturate a SIMD.
// Numerics per pixel unchanged (numpy-exact pairwise norms, sequential-FMA dot).

#define C_DIM   64
#define N_EMB   512
#define HALF    256                  // codes per LDS half
#define HW      4096                 // 64*64
#define N_PIX   (32 * HW)            // 131072
#define ZQ_OFF  1
#define IDX_OFF (1 + N_PIX * C_DIM)  // 1 + 8388608

__global__ __launch_bounds__(128, 1) void vq_main(
    const float* __restrict__ z,
    const float* __restrict__ cb,
    float* __restrict__ out,
    float* __restrict__ ws)
{
    __shared__ float4 ecb4[HALF * C_DIM / 4];  // 64KB: one half of the codebook
    __shared__ float  esum[N_EMB];             // b_j = np.sum(cb*cb,1), numpy-exact
    __shared__ float  wsum[2];

    const int t = threadIdx.x;                 // 0..127

    // b_j with numpy pairwise_sum(n=64) semantics: 8 accs, rounded mul, tree.
    for (int j = t; j < N_EMB; j += 128) {
        const float* e = cb + j * C_DIM;
        float r[8];
        #pragma unroll
        for (int i = 0; i < 8; ++i) r[i] = __fmul_rn(e[i], e[i]);
        #pragma unroll
        for (int k = 8; k < 64; k += 8) {
            #pragma unroll
            for (int i = 0; i < 8; ++i)
                r[i] = __fadd_rn(r[i], __fmul_rn(e[k + i], e[k + i]));
        }
        esum[j] = __fadd_rn(
            __fadd_rn(__fadd_rn(r[0], r[1]), __fadd_rn(r[2], r[3])),
            __fadd_rn(__fadd_rn(r[4], r[5]), __fadd_rn(r[6], r[7])));
    }

    // Two pixels per thread: p0 = base+t, p1 = base+128+t (same batch, both
    // coalesced per wave). 512 blocks x 256 pixels = 131072.
    const int base = blockIdx.x * 256;
    const int p0   = base + t;
    const int b    = p0 >> 12;
    const int hw0  = p0 & (HW - 1);
    const float* zp = z + (size_t)b * (C_DIM * HW) + hw0;

    float zA[C_DIM], zB[C_DIM];
    #pragma unroll
    for (int c = 0; c < C_DIM; ++c) zA[c] = zp[(size_t)c * HW];
    #pragma unroll
    for (int c = 0; c < C_DIM; ++c) zB[c] = zp[(size_t)c * HW + 128];
    #pragma unroll
    for (int c = 0; c < C_DIM; ++c) asm volatile("" : "+v"(zA[c]));
    #pragma unroll
    for (int c = 0; c < C_DIM; ++c) asm volatile("" : "+v"(zB[c]));

    // a_p per pixel, numpy-exact pattern.
    float apA, apB;
    {
        float r[8], s[8];
        #pragma unroll
        for (int i = 0; i < 8; ++i) { r[i] = __fmul_rn(zA[i], zA[i]);
                                      s[i] = __fmul_rn(zB[i], zB[i]); }
        #pragma unroll
        for (int k = 8; k < 64; k += 8) {
            #pragma unroll
            for (int i = 0; i < 8; ++i) {
                r[i] = __fadd_rn(r[i], __fmul_rn(zA[k + i], zA[k + i]));
                s[i] = __fadd_rn(s[i], __fmul_rn(zB[k + i], zB[k + i]));
            }
        }
        apA = __fadd_rn(
            __fadd_rn(__fadd_rn(r[0], r[1]), __fadd_rn(r[2], r[3])),
            __fadd_rn(__fadd_rn(r[4], r[5]), __fadd_rn(r[6], r[7])));
        apB = __fadd_rn(
            __fadd_rn(__fadd_rn(s[0], s[1]), __fadd_rn(s[2], s[3])),
            __fadd_rn(__fadd_rn(s[4], s[5]), __fadd_rn(s[6], s[7])));
    }

    // Argmin over 512 codes in two LDS-staged halves. Per pixel (bit-exact):
    //   dot  = sequential FMA chain c=0..63;  dist = (ap + b_j) - 2*dot
    float bestA = 3.0e38f, bestB = 3.0e38f;
    int   bjA   = 0,       bjB   = 0;
    for (int h = 0; h < 2; ++h) {
        __syncthreads();   // prev half consumed / esum ready
        {   // stage 64KB: 4096 float4, 32 per thread, coalesced
            const float4* src = (const float4*)(cb + h * (HALF * C_DIM));
            #pragma unroll
            for (int i = 0; i < 32; ++i)
                ecb4[t + i * 128] = src[t + i * 128];
        }
        __syncthreads();

        const float* __restrict__ eb0 = (const float*)ecb4;
        #pragma unroll 2
        for (int jj = 0; jj < HALF; ++jj) {
            const int j = h * HALF + jj;
            const float* __restrict__ e = eb0 + jj * C_DIM;  // uniform -> broadcast
            float aA = 0.0f, aB = 0.0f;
            #pragma unroll
            for (int c = 0; c < C_DIM; ++c) {
                float ec = e[c];
                aA = __fmaf_rn(zA[c], ec, aA);
                aB = __fmaf_rn(zB[c], ec, aB);
            }
            float dA = __fsub_rn(__fadd_rn(apA, esum[j]), __fmul_rn(2.0f, aA));
            float dB = __fsub_rn(__fadd_rn(apB, esum[j]), __fmul_rn(2.0f, aB));
            if (dA < bestA) { bestA = dA; bjA = j; }   // strict '<' == np first-min
            if (dB < bestB) { bestB = dB; bjB = j; }
        }
    }

    // Epilogue: gather winning codes (L2-resident), write z_q in NCHW
    // (coalesced per c-plane), accumulate MSE partials.
    const float* __restrict__ eA = cb + bjA * C_DIM;
    const float* __restrict__ eB = cb + bjB * C_DIM;
    float* zq = out + ZQ_OFF + (size_t)b * (C_DIM * HW) + hw0;
    float ls = 0.f;
    #pragma unroll
    for (int c = 0; c < C_DIM; ++c) {
        float ecA = eA[c], ecB = eB[c];
        zq[(size_t)c * HW]       = ecA;
        zq[(size_t)c * HW + 128] = ecB;
        float dfA = ecA - zA[c];
        float dfB = ecB - zB[c];
        ls = fmaf(dfA, dfA, ls);
        ls = fmaf(dfB, dfB, ls);
    }
    out[IDX_OFF + p0]       = (float)bjA;
    out[IDX_OFF + p0 + 128] = (float)bjB;

    // Block-reduce loss partial -> ws[blockIdx.x] (2 waves).
    #pragma unroll
    for (int off = 32; off; off >>= 1) ls += __shfl_down(ls, off, 64);
    const int lane = t & 63, wid = t >> 6;
    if (lane == 0) wsum[wid] = ls;
    __syncthreads();
    if (t == 0) ws[blockIdx.x] = wsum[0] + wsum[1];
}

__global__ __launch_bounds__(256) void vq_loss(
    const float* __restrict__ ws, float* __restrict__ out)
{
    __shared__ float sm[4];
    float v = ws[threadIdx.x] + ws[threadIdx.x + 256];
    #pragma unroll
    for (int off = 32; off; off >>= 1) v += __shfl_down(v, off, 64);
    const int lane = threadIdx.x & 63, wid = threadIdx.x >> 6;
    if (lane == 0) sm[wid] = v;
    __syncthreads();
    if (threadIdx.x == 0)
        out[0] = ((sm[0] + sm[1]) + (sm[2] + sm[3])) * (1.0f / 8388608.0f);
}

extern "C" void kernel_launch(void* const* d_in, const int* in_sizes, int n_in,
                              void* d_out, int out_size, void* d_ws, size_t ws_size,
                              hipStream_t stream)
{
    const float* z  = (const float*)d_in[0];   // 8388608 f32
    const float* cb = (const float*)d_in[1];   // 32768 f32
    float* out = (float*)d_out;
    float* ws  = (float*)d_ws;                 // 512 f32 partials

    vq_main<<<N_PIX / 256, 128, 0, stream>>>(z, cb, out, ws);
    vq_loss<<<1, 256, 0, stream>>>(ws, out);
}

// Round 7
// 211.592 us; speedup vs baseline: 1.0670x; 1.0670x over previous
//
#include <hip/hip_runtime.h>

// VectorQuantizer on MI355X (gfx950), fp32 — bit-mimics the numpy fp32 reference.
// Round 6: round 5's 2px/thread regressed because 128-thr blocks x 512 grid left
// 1 wave/SIMD (VALUBusy 34% — no partner wave to hide LDS latency). Fix the
// geometry: 256 blocks x 256 threads x 2 px/thread = exactly 1 block/CU,
// 8 waves/CU = 2 waves/SIMD (round 4's proven TLP) while keeping the 2x
// FMA-per-ds_read ratio and ILP=2. Numerics identical to rounds 3-5 (passed).

#define C_DIM   64
#define N_EMB   512
#define HALF    256                  // codes per LDS half
#define HW      4096                 // 64*64
#define N_PIX   (32 * HW)            // 131072
#define ZQ_OFF  1
#define IDX_OFF (1 + N_PIX * C_DIM)  // 1 + 8388608

__global__ __launch_bounds__(256, 2) void vq_main(
    const float* __restrict__ z,
    const float* __restrict__ cb,
    float* __restrict__ out,
    float* __restrict__ ws)
{
    __shared__ float4 ecb4[HALF * C_DIM / 4];  // 64KB: one half of the codebook
    __shared__ float  esum[N_EMB];             // b_j = np.sum(cb*cb,1), numpy-exact
    __shared__ float  wsum[4];

    const int t = threadIdx.x;                 // 0..255

    // b_j with numpy pairwise_sum(n=64) semantics: 8 accs, rounded mul, tree.
    for (int j = t; j < N_EMB; j += 256) {
        const float* e = cb + j * C_DIM;
        float r[8];
        #pragma unroll
        for (int i = 0; i < 8; ++i) r[i] = __fmul_rn(e[i], e[i]);
        #pragma unroll
        for (int k = 8; k < 64; k += 8) {
            #pragma unroll
            for (int i = 0; i < 8; ++i)
                r[i] = __fadd_rn(r[i], __fmul_rn(e[k + i], e[k + i]));
        }
        esum[j] = __fadd_rn(
            __fadd_rn(__fadd_rn(r[0], r[1]), __fadd_rn(r[2], r[3])),
            __fadd_rn(__fadd_rn(r[4], r[5]), __fadd_rn(r[6], r[7])));
    }

    // Two pixels per thread: p0 = base+t, p1 = base+256+t (same batch since
    // 512 | 4096; both coalesced per wave). 256 blocks x 512 pixels = 131072.
    const int base = blockIdx.x * 512;
    const int p0   = base + t;
    const int b    = p0 >> 12;
    const int hw0  = p0 & (HW - 1);
    const float* zp = z + (size_t)b * (C_DIM * HW) + hw0;

    float zA[C_DIM], zB[C_DIM];
    #pragma unroll
    for (int c = 0; c < C_DIM; ++c) zA[c] = zp[(size_t)c * HW];
    #pragma unroll
    for (int c = 0; c < C_DIM; ++c) zB[c] = zp[(size_t)c * HW + 256];
    #pragma unroll
    for (int c = 0; c < C_DIM; ++c) asm volatile("" : "+v"(zA[c]));
    #pragma unroll
    for (int c = 0; c < C_DIM; ++c) asm volatile("" : "+v"(zB[c]));

    // a_p per pixel, numpy-exact pattern.
    float apA, apB;
    {
        float r[8], s[8];
        #pragma unroll
        for (int i = 0; i < 8; ++i) { r[i] = __fmul_rn(zA[i], zA[i]);
                                      s[i] = __fmul_rn(zB[i], zB[i]); }
        #pragma unroll
        for (int k = 8; k < 64; k += 8) {
            #pragma unroll
            for (int i = 0; i < 8; ++i) {
                r[i] = __fadd_rn(r[i], __fmul_rn(zA[k + i], zA[k + i]));
                s[i] = __fadd_rn(s[i], __fmul_rn(zB[k + i], zB[k + i]));
            }
        }
        apA = __fadd_rn(
            __fadd_rn(__fadd_rn(r[0], r[1]), __fadd_rn(r[2], r[3])),
            __fadd_rn(__fadd_rn(r[4], r[5]), __fadd_rn(r[6], r[7])));
        apB = __fadd_rn(
            __fadd_rn(__fadd_rn(s[0], s[1]), __fadd_rn(s[2], s[3])),
            __fadd_rn(__fadd_rn(s[4], s[5]), __fadd_rn(s[6], s[7])));
    }

    // Argmin over 512 codes in two LDS-staged halves. Per pixel (bit-exact):
    //   dot  = sequential FMA chain c=0..63;  dist = (ap + b_j) - 2*dot
    float bestA = 3.0e38f, bestB = 3.0e38f;
    int   bjA   = 0,       bjB   = 0;
    for (int h = 0; h < 2; ++h) {
        __syncthreads();   // prev half consumed / esum ready
        {   // stage 64KB: 4096 float4, 16 per thread, coalesced
            const float4* src = (const float4*)(cb + h * (HALF * C_DIM));
            #pragma unroll
            for (int i = 0; i < 16; ++i)
                ecb4[t + i * 256] = src[t + i * 256];
        }
        __syncthreads();

        const float* __restrict__ eb0 = (const float*)ecb4;
        #pragma unroll 2
        for (int jj = 0; jj < HALF; ++jj) {
            const int j = h * HALF + jj;
            const float* __restrict__ e = eb0 + jj * C_DIM;  // uniform -> broadcast
            float aA = 0.0f, aB = 0.0f;
            #pragma unroll
            for (int c = 0; c < C_DIM; ++c) {
                float ec = e[c];
                aA = __fmaf_rn(zA[c], ec, aA);
                aB = __fmaf_rn(zB[c], ec, aB);
            }
            float dA = __fsub_rn(__fadd_rn(apA, esum[j]), __fmul_rn(2.0f, aA));
            float dB = __fsub_rn(__fadd_rn(apB, esum[j]), __fmul_rn(2.0f, aB));
            if (dA < bestA) { bestA = dA; bjA = j; }   // strict '<' == np first-min
            if (dB < bestB) { bestB = dB; bjB = j; }
        }
    }

    // Epilogue: gather winning codes (L2-resident), write z_q in NCHW
    // (coalesced per c-plane), accumulate MSE partials.
    const float* __restrict__ eA = cb + bjA * C_DIM;
    const float* __restrict__ eB = cb + bjB * C_DIM;
    float* zq = out + ZQ_OFF + (size_t)b * (C_DIM * HW) + hw0;
    float ls = 0.f;
    #pragma unroll
    for (int c = 0; c < C_DIM; ++c) {
        float ecA = eA[c], ecB = eB[c];
        zq[(size_t)c * HW]       = ecA;
        zq[(size_t)c * HW + 256] = ecB;
        float dfA = ecA - zA[c];
        float dfB = ecB - zB[c];
        ls = fmaf(dfA, dfA, ls);
        ls = fmaf(dfB, dfB, ls);
    }
    out[IDX_OFF + p0]       = (float)bjA;
    out[IDX_OFF + p0 + 256] = (float)bjB;

    // Block-reduce loss partial -> ws[blockIdx.x] (4 waves).
    #pragma unroll
    for (int off = 32; off; off >>= 1) ls += __shfl_down(ls, off, 64);
    const int lane = t & 63, wid = t >> 6;
    if (lane == 0) wsum[wid] = ls;
    __syncthreads();
    if (t == 0)
        ws[blockIdx.x] = (wsum[0] + wsum[1]) + (wsum[2] + wsum[3]);
}

__global__ __launch_bounds__(256) void vq_loss(
    const float* __restrict__ ws, float* __restrict__ out)
{
    __shared__ float sm[4];
    float v = ws[threadIdx.x];              // 256 block partials
    #pragma unroll
    for (int off = 32; off; off >>= 1) v += __shfl_down(v, off, 64);
    const int lane = threadIdx.x & 63, wid = threadIdx.x >> 6;
    if (lane == 0) sm[wid] = v;
    __syncthreads();
    if (threadIdx.x == 0)
        out[0] = ((sm[0] + sm[1]) + (sm[2] + sm[3])) * (1.0f / 8388608.0f);
}

extern "C" void kernel_launch(void* const* d_in, const int* in_sizes, int n_in,
                              void* d_out, int out_size, void* d_ws, size_t ws_size,
                              hipStream_t stream)
{
    const float* z  = (const float*)d_in[0];   // 8388608 f32
    const float* cb = (const float*)d_in[1];   // 32768 f32
    float* out = (float*)d_out;
    float* ws  = (float*)d_ws;                 // 256 f32 partials

    vq_main<<<N_PIX / 512, 256, 0, stream>>>(z, cb, out, ws);
    vq_loss<<<1, 256, 0, stream>>>(ws, out);
}

// Round 8
// 173.815 us; speedup vs baseline: 1.2989x; 1.2173x over previous
//
#include <hip/hip_runtime.h>

// VectorQuantizer on MI355X (gfx950), fp32 — bit-mimics the numpy fp32 reference.
// Round 7: (a) j-split — 2 threads per pixel, 256 codes each -> 4096 waves =
// 4 waves/SIMD (rounds 5/6 proved 1 wave/SIMD stalls at 35% regardless of ILP);
// (b) codebook supplied via the SCALAR pipe: `half` comes from readfirstlane so
// j is provably wave-uniform -> s_load_dwordx16 + SGPR-operand v_fmac, zero LDS
// and zero VMEM in the inner loop. Numerics per pixel identical to rounds 3-6
// (numpy-exact pairwise norms, sequential-FMA dot, (ap+b_j)-2*dot combine).

#define C_DIM   64
#define N_EMB   512
#define HW      4096                 // 64*64
#define N_PIX   (32 * HW)            // 131072
#define ZQ_OFF  1
#define IDX_OFF (1 + N_PIX * C_DIM)  // 1 + 8388608
#define PPB     128                  // pixels per block (256 threads, 2 per pixel)
#define NBLK    (N_PIX / PPB)        // 1024 blocks

__global__ __launch_bounds__(256, 4) void vq_main(
    const float* __restrict__ z,
    const float* __restrict__ cb,
    float* __restrict__ out,
    float* __restrict__ ws)
{
    __shared__ float esum[N_EMB];    // b_j = np.sum(cb*cb,1), numpy-exact
    __shared__ float mD[PPB];        // high-half best dist
    __shared__ int   mJ[PPB];        // high-half best index
    __shared__ float wsum[2];

    const int t = threadIdx.x;       // 0..255

    // b_j with numpy pairwise_sum(n=64) semantics: 8 accs, rounded mul, tree.
    for (int j = t; j < N_EMB; j += 256) {
        const float* e = cb + j * C_DIM;
        float r[8];
        #pragma unroll
        for (int i = 0; i < 8; ++i) r[i] = __fmul_rn(e[i], e[i]);
        #pragma unroll
        for (int k = 8; k < 64; k += 8) {
            #pragma unroll
            for (int i = 0; i < 8; ++i)
                r[i] = __fadd_rn(r[i], __fmul_rn(e[k + i], e[k + i]));
        }
        esum[j] = __fadd_rn(
            __fadd_rn(__fadd_rn(r[0], r[1]), __fadd_rn(r[2], r[3])),
            __fadd_rn(__fadd_rn(r[4], r[5]), __fadd_rn(r[6], r[7])));
    }

    // Thread -> (pixel, codebook half). half is wave-uniform (wave=64, 128|t
    // boundary); readfirstlane makes that PROVABLE -> j uniform -> s_load.
    const int half = __builtin_amdgcn_readfirstlane(t >> 7);   // 0 or 1
    const int tp   = t & (PPB - 1);
    const int p    = blockIdx.x * PPB + tp;
    const int b    = p >> 12;
    const int hw0  = p & (HW - 1);
    const float* zp = z + (size_t)b * (C_DIM * HW) + hw0;

    // z vector: 64 f32 pinned in VGPRs (asm = opaque def, no remat).
    float zr[C_DIM];
    #pragma unroll
    for (int c = 0; c < C_DIM; ++c) zr[c] = zp[(size_t)c * HW];
    #pragma unroll
    for (int c = 0; c < C_DIM; ++c) asm volatile("" : "+v"(zr[c]));

    // a_p = np.sum(zf*zf,1), numpy-exact pattern.
    float ap;
    {
        float r[8];
        #pragma unroll
        for (int i = 0; i < 8; ++i) r[i] = __fmul_rn(zr[i], zr[i]);
        #pragma unroll
        for (int k = 8; k < 64; k += 8) {
            #pragma unroll
            for (int i = 0; i < 8; ++i)
                r[i] = __fadd_rn(r[i], __fmul_rn(zr[k + i], zr[k + i]));
        }
        ap = __fadd_rn(
            __fadd_rn(__fadd_rn(r[0], r[1]), __fadd_rn(r[2], r[3])),
            __fadd_rn(__fadd_rn(r[4], r[5]), __fadd_rn(r[6], r[7])));
    }

    __syncthreads();   // esum fully written

    // Scan this thread's half of the codebook (bit-exact reference rounding):
    //   dot = sequential FMA chain c=0..63;  dist = (ap + b_j) - 2*dot
    const int j0 = half * (N_EMB / 2);
    float best = 3.0e38f;
    int   bj   = j0;
    for (int jj = 0; jj < N_EMB / 2; ++jj) {
        const int j = j0 + jj;
        const float* __restrict__ e = cb + (size_t)j * C_DIM;  // uniform -> s_load
        float acc = 0.0f;
        #pragma unroll
        for (int c = 0; c < C_DIM; ++c)
            acc = __fmaf_rn(zr[c], e[c], acc);
        float d = __fsub_rn(__fadd_rn(ap, esum[j]), __fmul_rn(2.0f, acc));
        if (d < best) { best = d; bj = j; }   // strict '<' == np first-min
    }

    // Merge halves: high half publishes, low half resolves (strict '<' keeps
    // the low half on ties == lower j == np.argmin first occurrence).
    if (half == 1) { mD[tp] = best; mJ[tp] = bj; }
    __syncthreads();

    float ls = 0.f;
    if (half == 0) {
        float dH = mD[tp];
        if (dH < best) { best = dH; bj = mJ[tp]; }

        // Epilogue: gather winning code (L2-resident), write z_q in NCHW
        // (coalesced per c-plane), accumulate MSE partial.
        const float* __restrict__ eb = cb + bj * C_DIM;
        float* zq = out + ZQ_OFF + (size_t)b * (C_DIM * HW) + hw0;
        #pragma unroll
        for (int c = 0; c < C_DIM; ++c) {
            float ec = eb[c];
            zq[(size_t)c * HW] = ec;
            float df = ec - zr[c];
            ls = fmaf(df, df, ls);
        }
        out[IDX_OFF + p] = (float)bj;

        // Wave-reduce loss partial (waves 0,1 are entirely half==0).
        #pragma unroll
        for (int off = 32; off; off >>= 1) ls += __shfl_down(ls, off, 64);
        if ((t & 63) == 0) wsum[t >> 6] = ls;
    }
    __syncthreads();
    if (t == 0) ws[blockIdx.x] = wsum[0] + wsum[1];
}

__global__ __launch_bounds__(256) void vq_loss(
    const float* __restrict__ ws, float* __restrict__ out)
{
    __shared__ float sm[4];
    float v = (ws[threadIdx.x]       + ws[threadIdx.x + 256])
            + (ws[threadIdx.x + 512] + ws[threadIdx.x + 768]);
    #pragma unroll
    for (int off = 32; off; off >>= 1) v += __shfl_down(v, off, 64);
    const int lane = threadIdx.x & 63, wid = threadIdx.x >> 6;
    if (lane == 0) sm[wid] = v;
    __syncthreads();
    if (threadIdx.x == 0)
        out[0] = ((sm[0] + sm[1]) + (sm[2] + sm[3])) * (1.0f / 8388608.0f);
}

extern "C" void kernel_launch(void* const* d_in, const int* in_sizes, int n_in,
                              void* d_out, int out_size, void* d_ws, size_t ws_size,
                              hipStream_t stream)
{
    const float* z  = (const float*)d_in[0];   // 8388608 f32
    const float* cb = (const float*)d_in[1];   // 32768 f32
    float* out = (float*)d_out;
    float* ws  = (float*)d_ws;                 // 1024 f32 partials

    vq_main<<<NBLK, 256, 0, stream>>>(z, cb, out, ws);
    vq_loss<<<1, 256, 0, stream>>>(ws, out);
}

// Round 9
// 142.381 us; speedup vs baseline: 1.5856x; 1.2208x over previous
//
#include <hip/hip_runtime.h>

// VectorQuantizer on MI355X (gfx950), fp32 — bit-mimics the numpy fp32 reference.
// Round 8: combine the two proven levers (never yet co-resident):
//   (a) 2 pixels/thread  -> 128 FMA per 16 LDS reads (2x round 4's ratio)
//   (b) j-split 2-way    -> 131072 threads = 8 waves/CU = 2 waves/SIMD
//       (rounds 5/6: 1 wave/SIMD stalls at 35%; round 4: 2 waves/SIMD = 72%)
// Needs the FULL 128KB codebook in LDS (both halves scanned concurrently):
// 137KB static LDS, one 512-thread block per CU. __launch_bounds__(512,2)
// gives a 256-VGPR cap so zA+zB (128 f32) stay in registers (round 7's
// VGPR=44 showed (256,4)'s 128-cap spilled z to scratch).
// Numerics per pixel identical to rounds 3-7 (numpy-exact pairwise norms,
// sequential-FMA dot, (ap+b_j)-2*dot combine, strict-< first-min).

#define C_DIM   64
#define N_EMB   512
#define HW      4096                 // 64*64
#define N_PIX   (32 * HW)            // 131072
#define ZQ_OFF  1
#define IDX_OFF (1 + N_PIX * C_DIM)  // 1 + 8388608
#define TPB     512                  // threads per block
#define PXB     512                  // pixels per block (2 per low/high thread pair)
#define NBLK    (N_PIX / PXB)        // 256 blocks -> 1 block/CU

__global__ __launch_bounds__(TPB, 2) void vq_main(
    const float* __restrict__ z,
    const float* __restrict__ cb,
    float* __restrict__ out,
    float* __restrict__ ws)
{
    __shared__ float4 ecb4[N_EMB * C_DIM / 4];  // 128KB: FULL codebook
    __shared__ float  esum[N_EMB];              // b_j = np.sum(cb*cb,1), numpy-exact
    __shared__ float  mD[PXB];                  // high-half best dist per pixel
    __shared__ int    mJ[PXB];                  // high-half best index per pixel
    __shared__ float  wsum[4];

    const int t = threadIdx.x;                  // 0..511

    // Stage full codebook: 8192 float4, 16 per thread, coalesced.
    {
        const float4* src = (const float4*)cb;
        #pragma unroll
        for (int i = 0; i < 16; ++i)
            ecb4[t + i * TPB] = src[t + i * TPB];
    }

    // b_j with numpy pairwise_sum(n=64) semantics: 8 accs, rounded mul, tree.
    {
        const int j = t;                        // one code per thread
        const float* e = cb + j * C_DIM;
        float r[8];
        #pragma unroll
        for (int i = 0; i < 8; ++i) r[i] = __fmul_rn(e[i], e[i]);
        #pragma unroll
        for (int k = 8; k < 64; k += 8) {
            #pragma unroll
            for (int i = 0; i < 8; ++i)
                r[i] = __fadd_rn(r[i], __fmul_rn(e[k + i], e[k + i]));
        }
        esum[j] = __fadd_rn(
            __fadd_rn(__fadd_rn(r[0], r[1]), __fadd_rn(r[2], r[3])),
            __fadd_rn(__fadd_rn(r[4], r[5]), __fadd_rn(r[6], r[7])));
    }

    // Thread -> (pixel pair, codebook half). jhalf is wave-uniform (256 | t).
    const int jhalf = t >> 8;                   // 0 or 1
    const int tp    = t & 255;                  // pixel-pair id in block
    const int p0    = blockIdx.x * PXB + tp;    // second pixel = p0 + 256
    const int b     = p0 >> 12;                 // same batch for both (512 | 4096)
    const int hw0   = p0 & (HW - 1);
    const float* zp = z + (size_t)b * (C_DIM * HW) + hw0;

    // Two z vectors: 128 f32 pinned in VGPRs.
    float zA[C_DIM], zB[C_DIM];
    #pragma unroll
    for (int c = 0; c < C_DIM; ++c) zA[c] = zp[(size_t)c * HW];
    #pragma unroll
    for (int c = 0; c < C_DIM; ++c) zB[c] = zp[(size_t)c * HW + 256];
    #pragma unroll
    for (int c = 0; c < C_DIM; ++c) asm volatile("" : "+v"(zA[c]));
    #pragma unroll
    for (int c = 0; c < C_DIM; ++c) asm volatile("" : "+v"(zB[c]));

    // a_p per pixel, numpy-exact pattern.
    float apA, apB;
    {
        float r[8], s[8];
        #pragma unroll
        for (int i = 0; i < 8; ++i) { r[i] = __fmul_rn(zA[i], zA[i]);
                                      s[i] = __fmul_rn(zB[i], zB[i]); }
        #pragma unroll
        for (int k = 8; k < 64; k += 8) {
            #pragma unroll
            for (int i = 0; i < 8; ++i) {
                r[i] = __fadd_rn(r[i], __fmul_rn(zA[k + i], zA[k + i]));
                s[i] = __fadd_rn(s[i], __fmul_rn(zB[k + i], zB[k + i]));
            }
        }
        apA = __fadd_rn(
            __fadd_rn(__fadd_rn(r[0], r[1]), __fadd_rn(r[2], r[3])),
            __fadd_rn(__fadd_rn(r[4], r[5]), __fadd_rn(r[6], r[7])));
        apB = __fadd_rn(
            __fadd_rn(__fadd_rn(s[0], s[1]), __fadd_rn(s[2], s[3])),
            __fadd_rn(__fadd_rn(s[4], s[5]), __fadd_rn(s[6], s[7])));
    }

    __syncthreads();   // codebook + esum staged

    // Scan this thread's half of the codebook for BOTH pixels (bit-exact):
    //   dot = sequential FMA chain c=0..63;  dist = (ap + b_j) - 2*dot
    const int j0 = jhalf << 8;                  // 0 or 256
    const float* __restrict__ eb0 = (const float*)ecb4;
    float bestA = 3.0e38f, bestB = 3.0e38f;
    int   bjA   = j0,      bjB   = j0;
    #pragma unroll 2
    for (int jj = 0; jj < N_EMB / 2; ++jj) {
        const int j = j0 + jj;
        const float* __restrict__ e = eb0 + (size_t)j * C_DIM;  // uniform -> broadcast
        float aA = 0.0f, aB = 0.0f;
        #pragma unroll
        for (int c = 0; c < C_DIM; ++c) {
            float ec = e[c];
            aA = __fmaf_rn(zA[c], ec, aA);
            aB = __fmaf_rn(zB[c], ec, aB);
        }
        float dA = __fsub_rn(__fadd_rn(apA, esum[j]), __fmul_rn(2.0f, aA));
        float dB = __fsub_rn(__fadd_rn(apB, esum[j]), __fmul_rn(2.0f, aB));
        if (dA < bestA) { bestA = dA; bjA = j; }   // strict '<' == np first-min
        if (dB < bestB) { bestB = dB; bjB = j; }
    }

    // Merge halves: high half publishes; low half resolves (strict '<' keeps
    // the low half on ties == lower j == np.argmin first occurrence).
    if (jhalf == 1) {
        mD[tp]       = bestA;  mJ[tp]       = bjA;
        mD[tp + 256] = bestB;  mJ[tp + 256] = bjB;
    }
    __syncthreads();

    float ls = 0.f;
    if (jhalf == 0) {
        float dHA = mD[tp],       dHB = mD[tp + 256];
        if (dHA < bestA) { bestA = dHA; bjA = mJ[tp]; }
        if (dHB < bestB) { bestB = dHB; bjB = mJ[tp + 256]; }

        // Epilogue: gather winning codes (L2-resident), write z_q in NCHW
        // (coalesced per c-plane), accumulate MSE partials.
        const float* __restrict__ eA = cb + bjA * C_DIM;
        const float* __restrict__ eB = cb + bjB * C_DIM;
        float* zq = out + ZQ_OFF + (size_t)b * (C_DIM * HW) + hw0;
        #pragma unroll
        for (int c = 0; c < C_DIM; ++c) {
            float ecA = eA[c], ecB = eB[c];
            zq[(size_t)c * HW]       = ecA;
            zq[(size_t)c * HW + 256] = ecB;
            float dfA = ecA - zA[c];
            float dfB = ecB - zB[c];
            ls = fmaf(dfA, dfA, ls);
            ls = fmaf(dfB, dfB, ls);
        }
        out[IDX_OFF + p0]       = (float)bjA;
        out[IDX_OFF + p0 + 256] = (float)bjB;

        // Wave-reduce loss partial (waves 0-3 are entirely jhalf==0).
        #pragma unroll
        for (int off = 32; off; off >>= 1) ls += __shfl_down(ls, off, 64);
        if ((t & 63) == 0) wsum[t >> 6] = ls;
    }
    __syncthreads();
    if (t == 0)
        ws[blockIdx.x] = (wsum[0] + wsum[1]) + (wsum[2] + wsum[3]);
}

__global__ __launch_bounds__(256) void vq_loss(
    const float* __restrict__ ws, float* __restrict__ out)
{
    __shared__ float sm[4];
    float v = ws[threadIdx.x];              // 256 block partials
    #pragma unroll
    for (int off = 32; off; off >>= 1) v += __shfl_down(v, off, 64);
    const int lane = threadIdx.x & 63, wid = threadIdx.x >> 6;
    if (lane == 0) sm[wid] = v;
    __syncthreads();
    if (threadIdx.x == 0)
        out[0] = ((sm[0] + sm[1]) + (sm[2] + sm[3])) * (1.0f / 8388608.0f);
}

extern "C" void kernel_launch(void* const* d_in, const int* in_sizes, int n_in,
                              void* d_out, int out_size, void* d_ws, size_t ws_size,
                              hipStream_t stream)
{
    const float* z  = (const float*)d_in[0];   // 8388608 f32
    const float* cb = (const float*)d_in[1];   // 32768 f32
    float* out = (float*)d_out;
    float* ws  = (float*)d_ws;                 // 256 f32 partials

    vq_main<<<NBLK, TPB, 0, stream>>>(z, cb, out, ws);
    vq_loss<<<1, 256, 0, stream>>>(ws, out);
}

// Round 10
// 73.222 us; speedup vs baseline: 3.0833x; 1.9445x over previous
//
#include <hip/hip_runtime.h>

// VectorQuantizer on MI355X (gfx950) — MFMA candidate scan + exact numpy rescore.
// Phase 1 (matrix pipe): dist_approx = esum - 2*(z.e) via split-bf16 (hi+lo, 3
// passes) mfma_f32_16x16x32_bf16; per-lane top-3 candidates as sortable keys.
// Phase 2 (exact): owner lane rescores candidates within 4e-5 of approx-min
// using the bit-exact numpy fp32 arithmetic proven in rounds 3-8, then writes
// z_q / idx / loss. Codebook hi/lo staged in LDS with XOR swizzle (T2).

#define C_DIM   64
#define N_EMB   512
#define HW      4096
#define N_PIX   (32 * HW)            // 131072
#define ZQ_OFF  1
#define IDX_OFF (1 + N_PIX * C_DIM)

typedef short  short8 __attribute__((ext_vector_type(8)));
typedef float  f32x4  __attribute__((ext_vector_type(4)));
union FragU { unsigned u[4]; short8 s8; uint4 u4; };

__device__ __forceinline__ unsigned short f2bf(float x) {   // RNE f32->bf16
    unsigned u = __float_as_uint(x);
    return (unsigned short)((u + 0x7fffu + ((u >> 16) & 1u)) >> 16);
}
__device__ __forceinline__ float bf2f(unsigned short h) {
    return __uint_as_float(((unsigned)h) << 16);
}
__device__ __forceinline__ unsigned umn(unsigned a, unsigned b){ return a<b?a:b; }
__device__ __forceinline__ unsigned umx(unsigned a, unsigned b){ return a>b?a:b; }
__device__ __forceinline__ float kdec(unsigned k) {          // sortable-key -> float
    unsigned u = k & 0xFFFFFE00u;
    return ((int)u < 0) ? __uint_as_float(u ^ 0x80000000u) : __uint_as_float(~u);
}

__global__ __launch_bounds__(512, 2) void vq_main(
    const float* __restrict__ z,
    const float* __restrict__ cb,
    float* __restrict__ out,
    float* __restrict__ ws)
{
    __shared__ unsigned cbh[N_EMB * 32];   // 64KB codebook hi (bf16 pairs, swizzled)
    __shared__ unsigned cbl[N_EMB * 32];   // 64KB codebook lo
    __shared__ float    esh[N_EMB];        // numpy-exact ||e_j||^2
    __shared__ float    wsum[8];

    const int t = threadIdx.x;             // 0..511

    // ---- Stage codebook: thread t owns code row t ----
    {
        const float* e = cb + t * C_DIM;
        float ev[64];
        #pragma unroll
        for (int q = 0; q < 16; ++q) {
            float4 v = ((const float4*)e)[q];
            ev[4*q+0]=v.x; ev[4*q+1]=v.y; ev[4*q+2]=v.z; ev[4*q+3]=v.w;
        }
        // esum: numpy pairwise_sum(n=64): 8 accs, rounded mul, tree combine
        float r[8];
        #pragma unroll
        for (int i = 0; i < 8; ++i) r[i] = __fmul_rn(ev[i], ev[i]);
        #pragma unroll
        for (int k = 8; k < 64; k += 8) {
            #pragma unroll
            for (int i = 0; i < 8; ++i)
                r[i] = __fadd_rn(r[i], __fmul_rn(ev[k+i], ev[k+i]));
        }
        esh[t] = __fadd_rn(
            __fadd_rn(__fadd_rn(r[0],r[1]), __fadd_rn(r[2],r[3])),
            __fadd_rn(__fadd_rn(r[4],r[5]), __fadd_rn(r[6],r[7])));
        // split hi/lo bf16, pack pairs (c even low, c odd high)
        unsigned hw_[32], lw_[32];
        #pragma unroll
        for (int w2 = 0; w2 < 32; ++w2) {
            float x0 = ev[2*w2], x1 = ev[2*w2+1];
            unsigned short h0 = f2bf(x0), h1 = f2bf(x1);
            float r0 = x0 - bf2f(h0), r1 = x1 - bf2f(h1);
            unsigned short g0 = f2bf(r0), g1 = f2bf(r1);
            hw_[w2] = (unsigned)h0 | ((unsigned)h1 << 16);
            lw_[w2] = (unsigned)g0 | ((unsigned)g1 << 16);
        }
        const int rs = t & 7;              // XOR swizzle (16B granules)
        #pragma unroll
        for (int g = 0; g < 8; ++g) {
            int g2 = g ^ rs;
            *(uint4*)&cbh[t*32 + g2*4] =
                make_uint4(hw_[4*g], hw_[4*g+1], hw_[4*g+2], hw_[4*g+3]);
            *(uint4*)&cbl[t*32 + g2*4] =
                make_uint4(lw_[4*g], lw_[4*g+1], lw_[4*g+2], lw_[4*g+3]);
        }
    }
    __syncthreads();

    const int l   = t & 63;
    const int wv  = t >> 6;                // wave 0..7
    const int lg  = l >> 4;                // k-chunk group 0..3
    const int li  = l & 15;                // pixel col / code row within tile
    const int bb  = blockIdx.x >> 3;       // batch (512 px per block, 4096 per b)
    const int g20 = (0*4 + lg) ^ (l & 7);  // swizzled granule, kstep 0
    const int g21 = (1*4 + lg) ^ (l & 7);  // swizzled granule, kstep 1
    const int jb  = lg * 4;
    float ls = 0.f;

    for (int pt = 0; pt < 4; ++pt) {
        const int px0 = blockIdx.x * 512 + (wv*4 + pt) * 16;
        const int px  = px0 + li;
        const int col = px & (HW - 1);
        const float* zb = z + (size_t)bb * (C_DIM * HW) + col;

        // ---- B-fragments: z hi/lo bf16, lane supplies c = s*32 + lg*8 + i ----
        FragU bh0, bl0, bh1, bl1;
        {
            const float* zc0 = zb + (size_t)(lg * 8) * HW;
            const float* zc1 = zb + (size_t)(32 + lg * 8) * HW;
            #pragma unroll
            for (int w2 = 0; w2 < 4; ++w2) {
                float x0 = zc0[(size_t)(2*w2)*HW], x1 = zc0[(size_t)(2*w2+1)*HW];
                unsigned short h0 = f2bf(x0), h1 = f2bf(x1);
                float r0 = x0 - bf2f(h0), r1 = x1 - bf2f(h1);
                bh0.u[w2] = (unsigned)h0 | ((unsigned)h1 << 16);
                bl0.u[w2] = (unsigned)f2bf(r0) | ((unsigned)f2bf(r1) << 16);
                float y0 = zc1[(size_t)(2*w2)*HW], y1 = zc1[(size_t)(2*w2+1)*HW];
                unsigned short p0 = f2bf(y0), p1 = f2bf(y1);
                float s0 = y0 - bf2f(p0), s1 = y1 - bf2f(p1);
                bh1.u[w2] = (unsigned)p0 | ((unsigned)p1 << 16);
                bl1.u[w2] = (unsigned)f2bf(s0) | ((unsigned)f2bf(s1) << 16);
            }
        }

        // ---- MFMA scan: 32 code-tiles, per-lane top-3 sortable keys ----
        unsigned k1 = 0xFFFFFFFFu, k2 = 0xFFFFFFFFu, k3 = 0xFFFFFFFFu;
        #pragma unroll 4
        for (int T = 0; T < 32; ++T) {
            const int row0 = T*16 + li;
            FragU ah0, ah1, al0, al1;
            ah0.u4 = *(const uint4*)&cbh[row0*32 + g20*4];
            ah1.u4 = *(const uint4*)&cbh[row0*32 + g21*4];
            al0.u4 = *(const uint4*)&cbl[row0*32 + g20*4];
            al1.u4 = *(const uint4*)&cbl[row0*32 + g21*4];
            float4 es = *(const float4*)&esh[T*16 + jb];
            f32x4 acc = {0.f, 0.f, 0.f, 0.f};
            acc = __builtin_amdgcn_mfma_f32_16x16x32_bf16(ah0.s8, bh0.s8, acc, 0,0,0);
            acc = __builtin_amdgcn_mfma_f32_16x16x32_bf16(ah1.s8, bh1.s8, acc, 0,0,0);
            acc = __builtin_amdgcn_mfma_f32_16x16x32_bf16(ah0.s8, bl0.s8, acc, 0,0,0);
            acc = __builtin_amdgcn_mfma_f32_16x16x32_bf16(ah1.s8, bl1.s8, acc, 0,0,0);
            acc = __builtin_amdgcn_mfma_f32_16x16x32_bf16(al0.s8, bh0.s8, acc, 0,0,0);
            acc = __builtin_amdgcn_mfma_f32_16x16x32_bf16(al1.s8, bh1.s8, acc, 0,0,0);
            const int jT = T*16 + jb;
            #pragma unroll
            for (int r2 = 0; r2 < 4; ++r2) {
                float er = (r2==0) ? es.x : (r2==1) ? es.y : (r2==2) ? es.z : es.w;
                float d  = fmaf(-2.f, acc[r2], er);
                unsigned u = __float_as_uint(d);
                u ^= (unsigned)(((int)u) >> 31) | 0x80000000u;
                unsigned key = (u & 0xFFFFFE00u) | (unsigned)(jT + r2);
                unsigned m1 = umn(k1,key), M1 = umx(k1,key); k1 = m1;
                unsigned m2 = umn(k2,M1),  M2 = umx(k2,M1);  k2 = m2;
                k3 = umn(k3, M2);
            }
        }

        // ---- gather 12 candidates to owner lanes (l<16) ----
        unsigned c0 = k1, c1 = k2, c2 = k3;
        unsigned c3 = __shfl(k1, li+16, 64), c4  = __shfl(k2, li+16, 64), c5  = __shfl(k3, li+16, 64);
        unsigned c6 = __shfl(k1, li+32, 64), c7  = __shfl(k2, li+32, 64), c8  = __shfl(k3, li+32, 64);
        unsigned c9 = __shfl(k1, li+48, 64), c10 = __shfl(k2, li+48, 64), c11 = __shfl(k3, li+48, 64);

        if (l < 16) {
            // exact z reload (L2-hot) + numpy-exact ap
            float zr[64];
            #pragma unroll
            for (int c = 0; c < 64; ++c) zr[c] = zb[(size_t)c * HW];
            float ap;
            {
                float r[8];
                #pragma unroll
                for (int i = 0; i < 8; ++i) r[i] = __fmul_rn(zr[i], zr[i]);
                #pragma unroll
                for (int k = 8; k < 64; k += 8) {
                    #pragma unroll
                    for (int i = 0; i < 8; ++i)
                        r[i] = __fadd_rn(r[i], __fmul_rn(zr[k+i], zr[k+i]));
                }
                ap = __fadd_rn(
                    __fadd_rn(__fadd_rn(r[0],r[1]), __fadd_rn(r[2],r[3])),
                    __fadd_rn(__fadd_rn(r[4],r[5]), __fadd_rn(r[6],r[7])));
            }
            unsigned kmin = umn(umn(umn(c0,c1),umn(c2,c3)),
                                umn(umn(c4,c5),umn(umn(c6,c7),umn(umn(c8,c9),umn(c10,c11)))));
            const float thr = kdec(kmin) + 4.0e-5f;
            float bd = 3.0e38f; int bj = 1023;

            #define RESCORE(K) do {                                              \
                float da_ = kdec(K);                                             \
                if (da_ <= thr) {                                                \
                    int j_ = (int)((K) & 511u);                                  \
                    const float* er_ = cb + (size_t)j_ * 64;                     \
                    float a_ = 0.f;                                              \
                    _Pragma("unroll")                                            \
                    for (int c_ = 0; c_ < 64; ++c_)                              \
                        a_ = __fmaf_rn(zr[c_], er_[c_], a_);                     \
                    float dd_ = __fsub_rn(__fadd_rn(ap, esh[j_]),                \
                                          __fmul_rn(2.0f, a_));                  \
                    if (dd_ < bd || (dd_ == bd && j_ < bj)) { bd = dd_; bj = j_; } \
                }                                                                \
            } while (0)
            RESCORE(c0);  RESCORE(c1);  RESCORE(c2);  RESCORE(c3);
            RESCORE(c4);  RESCORE(c5);  RESCORE(c6);  RESCORE(c7);
            RESCORE(c8);  RESCORE(c9);  RESCORE(c10); RESCORE(c11);
            #undef RESCORE

            // epilogue: z_q (NCHW), idx, loss partial
            const float* ew = cb + (size_t)bj * 64;
            float* zq = out + ZQ_OFF + (size_t)bb * (C_DIM * HW) + col;
            #pragma unroll
            for (int c = 0; c < 64; ++c) {
                float ec = ew[c];
                zq[(size_t)c * HW] = ec;
                float df = ec - zr[c];
                ls = fmaf(df, df, ls);
            }
            out[IDX_OFF + px] = (float)bj;
        }
    }

    // ---- loss reduce: wave -> block -> ws ----
    #pragma unroll
    for (int off = 32; off; off >>= 1) ls += __shfl_down(ls, off, 64);
    if ((t & 63) == 0) wsum[wv] = ls;
    __syncthreads();
    if (t == 0) {
        float s = 0.f;
        #pragma unroll
        for (int i = 0; i < 8; ++i) s += wsum[i];
        ws[blockIdx.x] = s;
    }
}

__global__ __launch_bounds__(256) void vq_loss(
    const float* __restrict__ ws, float* __restrict__ out)
{
    __shared__ float sm[4];
    float v = ws[threadIdx.x];              // 256 block partials
    #pragma unroll
    for (int off = 32; off; off >>= 1) v += __shfl_down(v, off, 64);
    const int lane = threadIdx.x & 63, wid = threadIdx.x >> 6;
    if (lane == 0) sm[wid] = v;
    __syncthreads();
    if (threadIdx.x == 0)
        out[0] = ((sm[0] + sm[1]) + (sm[2] + sm[3])) * (1.0f / 8388608.0f);
}

extern "C" void kernel_launch(void* const* d_in, const int* in_sizes, int n_in,
                              void* d_out, int out_size, void* d_ws, size_t ws_size,
                              hipStream_t stream)
{
    const float* z  = (const float*)d_in[0];   // 8388608 f32
    const float* cb = (const float*)d_in[1];   // 32768 f32
    float* out = (float*)d_out;
    float* ws  = (float*)d_ws;                 // 256 f32 partials

    vq_main<<<N_PIX / 512, 512, 0, stream>>>(z, cb, out, ws);
    vq_loss<<<1, 256, 0, stream>>>(ws, out);
}

// Round 11
// 61.159 us; speedup vs baseline: 3.6914x; 1.1972x over previous
//
#include <hip/hip_runtime.h>

// VectorQuantizer on MI355X (gfx950) — single-pass fp16 MFMA scan + exact rescore.
// Key insight: codebook e ∈ (-1/512,1/512); pre-scaling e'=512e (exact, pow2)
// makes fp16 carry 2^-11 rel error on both operands -> ONE mfma_f32_16x16x32_f16
// pass matches the old 6-MFMA bf16 hi/lo tower's accuracy (scan err sigma ~7e-6).
// Codebook LDS halves to 64KB -> 2 blocks/CU (4 waves/SIMD), A-frags + esum
// reused across 2 pixel-tiles, keys positivity-folded (esum+0.5 staged).
// Phase 2 rescores candidates (top-3 x 4 lanes, window 1.2e-4) with the
// numpy-bit-exact fp32 arithmetic proven in rounds 3-9; loss taken from the
// winner's exact distance (= ||z-e||^2 incl. ap).

#define C_DIM   64
#define N_EMB   512
#define HW      4096
#define N_PIX   (32 * HW)            // 131072
#define ZQ_OFF  1
#define IDX_OFF (1 + N_PIX * C_DIM)
#define NBLK    512                  // 256 px per block, 2 blocks/CU

typedef _Float16 half8 __attribute__((ext_vector_type(8)));
typedef float    f32x4 __attribute__((ext_vector_type(4)));
union FragH { unsigned u[4]; half8 h8; uint4 u4; _Float16 h[8]; };

__device__ __forceinline__ unsigned umn(unsigned a, unsigned b){ return a<b?a:b; }
__device__ __forceinline__ unsigned umx(unsigned a, unsigned b){ return a>b?a:b; }

__global__ __launch_bounds__(512, 4) void vq_main(
    const float* __restrict__ z,
    const float* __restrict__ cb,
    float* __restrict__ out,
    float* __restrict__ ws)
{
    __shared__ unsigned cbh[N_EMB * 32];   // 64KB codebook as fp16 pairs (e*512), swizzled
    __shared__ float    esh5[N_EMB];       // esum + 0.5 (scan keys, positive d)
    __shared__ float    eshx[N_EMB];       // numpy-exact esum (rescore)
    __shared__ float    wsum[8];

    const int t = threadIdx.x;             // 0..511

    // ---- Stage codebook (thread t owns code row t) ----
    {
        const float* e = cb + t * C_DIM;
        float ev[64];
        #pragma unroll
        for (int q = 0; q < 16; ++q) {
            float4 v = ((const float4*)e)[q];
            ev[4*q+0]=v.x; ev[4*q+1]=v.y; ev[4*q+2]=v.z; ev[4*q+3]=v.w;
        }
        // numpy pairwise_sum(n=64): 8 accs, rounded mul, tree combine
        float r[8];
        #pragma unroll
        for (int i = 0; i < 8; ++i) r[i] = __fmul_rn(ev[i], ev[i]);
        #pragma unroll
        for (int k = 8; k < 64; k += 8) {
            #pragma unroll
            for (int i = 0; i < 8; ++i)
                r[i] = __fadd_rn(r[i], __fmul_rn(ev[k+i], ev[k+i]));
        }
        float es = __fadd_rn(
            __fadd_rn(__fadd_rn(r[0],r[1]), __fadd_rn(r[2],r[3])),
            __fadd_rn(__fadd_rn(r[4],r[5]), __fadd_rn(r[6],r[7])));
        eshx[t] = es;
        esh5[t] = es + 0.5f;
        // fp16(e*512) packed pairs; granule-XOR swizzle (16B, bank-spread)
        unsigned hw_[32];
        #pragma unroll
        for (int w2 = 0; w2 < 32; ++w2) {
            union { _Float16 h[2]; unsigned u; } pk;
            pk.h[0] = (_Float16)(ev[2*w2]   * 512.0f);
            pk.h[1] = (_Float16)(ev[2*w2+1] * 512.0f);
            hw_[w2] = pk.u;
        }
        const int rs = t & 7;
        #pragma unroll
        for (int g = 0; g < 8; ++g) {
            int g2 = g ^ rs;
            *(uint4*)&cbh[t*32 + g2*4] =
                make_uint4(hw_[4*g], hw_[4*g+1], hw_[4*g+2], hw_[4*g+3]);
        }
    }
    __syncthreads();

    const int l   = t & 63;
    const int wv  = t >> 6;                // wave 0..7
    const int lg  = l >> 4;                // k-chunk group 0..3
    const int li  = l & 15;                // pixel col / code row in tile
    const int bb  = blockIdx.x >> 4;       // batch (256 px per block)
    const int g20 = (lg)     ^ (li & 7);   // swizzled granule, k-step 0
    const int g21 = (4 + lg) ^ (li & 7);   // swizzled granule, k-step 1
    const int jb  = lg * 4;
    float ls = 0.f;

    // ---- B-fragments for BOTH pixel-tiles (pt=0,1): z as fp16, lane c-chunks ----
    const int px00 = blockIdx.x * 256 + (wv*2 + 0) * 16;
    const int px01 = blockIdx.x * 256 + (wv*2 + 1) * 16;
    const float* zb0 = z + (size_t)bb * (C_DIM * HW) + ((px00 + li) & (HW-1));
    const float* zb1 = z + (size_t)bb * (C_DIM * HW) + ((px01 + li) & (HW-1));
    FragH bA0, bA1, bB0, bB1;
    {
        const float* c0 = zb0 + (size_t)(lg*8) * HW;
        const float* c1 = zb0 + (size_t)(32 + lg*8) * HW;
        const float* c2 = zb1 + (size_t)(lg*8) * HW;
        const float* c3 = zb1 + (size_t)(32 + lg*8) * HW;
        #pragma unroll
        for (int i = 0; i < 8; ++i) {
            bA0.h[i] = (_Float16)c0[(size_t)i*HW];
            bA1.h[i] = (_Float16)c1[(size_t)i*HW];
            bB0.h[i] = (_Float16)c2[(size_t)i*HW];
            bB1.h[i] = (_Float16)c3[(size_t)i*HW];
        }
    }

    // ---- MFMA scan: 32 code-tiles; A-frags + esum shared across both pt ----
    unsigned k1A=0xFFFFFFFFu,k2A=0xFFFFFFFFu,k3A=0xFFFFFFFFu;
    unsigned k1B=0xFFFFFFFFu,k2B=0xFFFFFFFFu,k3B=0xFFFFFFFFu;
    #pragma unroll 4
    for (int T = 0; T < 32; ++T) {
        const int row = T*16 + li;
        FragH a0, a1;
        a0.u4 = *(const uint4*)&cbh[row*32 + g20*4];
        a1.u4 = *(const uint4*)&cbh[row*32 + g21*4];
        f32x4 es = *(const f32x4*)&esh5[T*16 + jb];
        f32x4 accA = {0.f,0.f,0.f,0.f}, accB = {0.f,0.f,0.f,0.f};
        accA = __builtin_amdgcn_mfma_f32_16x16x32_f16(a0.h8, bA0.h8, accA, 0,0,0);
        accA = __builtin_amdgcn_mfma_f32_16x16x32_f16(a1.h8, bA1.h8, accA, 0,0,0);
        accB = __builtin_amdgcn_mfma_f32_16x16x32_f16(a0.h8, bB0.h8, accB, 0,0,0);
        accB = __builtin_amdgcn_mfma_f32_16x16x32_f16(a1.h8, bB1.h8, accB, 0,0,0);
        const int jT = T*16 + jb;
        #pragma unroll
        for (int r2 = 0; r2 < 4; ++r2) {
            float er = (r2==0)?es[0]:(r2==1)?es[1]:(r2==2)?es[2]:es[3];
            // d = (esum+0.5) - (2/512)*dot'  > 0 -> uint-sortable directly
            float dA = __fmaf_rn(-0.00390625f, accA[r2], er);
            float dB = __fmaf_rn(-0.00390625f, accB[r2], er);
            unsigned keyA = (__float_as_uint(dA) & 0xFFFFFE00u) | (unsigned)(jT + r2);
            unsigned keyB = (__float_as_uint(dB) & 0xFFFFFE00u) | (unsigned)(jT + r2);
            unsigned m1,M1,m2,M2;
            m1=umn(k1A,keyA); M1=umx(k1A,keyA); k1A=m1;
            m2=umn(k2A,M1);   M2=umx(k2A,M1);   k2A=m2; k3A=umn(k3A,M2);
            m1=umn(k1B,keyB); M1=umx(k1B,keyB); k1B=m1;
            m2=umn(k2B,M1);   M2=umx(k2B,M1);   k2B=m2; k3B=umn(k3B,M2);
        }
    }

    // ---- per-pt: gather candidates, exact rescore, epilogue ----
    #pragma unroll
    for (int pt = 0; pt < 2; ++pt) {
        unsigned k1 = pt ? k1B : k1A, k2 = pt ? k2B : k2A, k3 = pt ? k3B : k3A;
        const float* zb = pt ? zb1 : zb0;
        const int px = (pt ? px01 : px00) + li;
        const int col = px & (HW-1);

        unsigned c0=k1, c1=k2, c2=k3;
        unsigned c3=__shfl(k1,li+16,64), c4 =__shfl(k2,li+16,64), c5 =__shfl(k3,li+16,64);
        unsigned c6=__shfl(k1,li+32,64), c7 =__shfl(k2,li+32,64), c8 =__shfl(k3,li+32,64);
        unsigned c9=__shfl(k1,li+48,64), c10=__shfl(k2,li+48,64), c11=__shfl(k3,li+48,64);

        int bj = 1023;
        if (l < 16) {
            float zr[64];
            #pragma unroll
            for (int c = 0; c < 64; ++c) zr[c] = zb[(size_t)c * HW];
            float ap;
            {   // numpy-exact ||z||^2
                float r[8];
                #pragma unroll
                for (int i = 0; i < 8; ++i) r[i] = __fmul_rn(zr[i], zr[i]);
                #pragma unroll
                for (int k = 8; k < 64; k += 8) {
                    #pragma unroll
                    for (int i = 0; i < 8; ++i)
                        r[i] = __fadd_rn(r[i], __fmul_rn(zr[k+i], zr[k+i]));
                }
                ap = __fadd_rn(
                    __fadd_rn(__fadd_rn(r[0],r[1]), __fadd_rn(r[2],r[3])),
                    __fadd_rn(__fadd_rn(r[4],r[5]), __fadd_rn(r[6],r[7])));
            }
            unsigned kmin = umn(umn(umn(c0,c1),umn(c2,c3)),
                                umn(umn(c4,c5),umn(umn(c6,c7),umn(umn(c8,c9),umn(c10,c11)))));
            const float thr = __uint_as_float(kmin & 0xFFFFFE00u) + 1.2e-4f;
            float bd = 3.0e38f;

            #define RESCORE(K) do {                                               \
                float da_ = __uint_as_float((K) & 0xFFFFFE00u);                   \
                if (da_ <= thr) {                                                 \
                    int j_ = (int)((K) & 511u);                                   \
                    const float* er_ = cb + (size_t)j_ * 64;                      \
                    float a_ = 0.f;                                               \
                    _Pragma("unroll")                                             \
                    for (int c_ = 0; c_ < 64; ++c_)                               \
                        a_ = __fmaf_rn(zr[c_], er_[c_], a_);                      \
                    float dd_ = __fsub_rn(__fadd_rn(ap, eshx[j_]),                \
                                          __fmul_rn(2.0f, a_));                   \
                    if (dd_ < bd || (dd_ == bd && j_ < bj)) { bd = dd_; bj = j_; }\
                }                                                                 \
            } while (0)
            RESCORE(c0);  RESCORE(c1);  RESCORE(c2);  RESCORE(c3);
            RESCORE(c4);  RESCORE(c5);  RESCORE(c6);  RESCORE(c7);
            RESCORE(c8);  RESCORE(c9);  RESCORE(c10); RESCORE(c11);
            #undef RESCORE

            out[IDX_OFF + px] = (float)bj;
            ls += bd;                       // loss term = exact ||z - e_bj||^2
        }

        // distributed z_q write: all 64 lanes, 4 c-planes x 16 px per instr
        int bjv = __shfl(bj, li, 64);
        const float* eb = cb + (size_t)bjv * 64;
        float* zq = out + ZQ_OFF + (size_t)bb * (C_DIM * HW) + col;
        const int cg = lg * 16;
        #pragma unroll
        for (int cc = 0; cc < 16; ++cc) {
            int c = cg + cc;
            zq[(size_t)c * HW] = eb[c];
        }
    }

    // ---- loss reduce: wave -> block -> ws ----
    #pragma unroll
    for (int off = 32; off; off >>= 1) ls += __shfl_down(ls, off, 64);
    if (l == 0) wsum[wv] = ls;
    __syncthreads();
    if (t == 0) {
        float s = 0.f;
        #pragma unroll
        for (int i = 0; i < 8; ++i) s += wsum[i];
        ws[blockIdx.x] = s;
    }
}

__global__ __launch_bounds__(256) void vq_loss(
    const float* __restrict__ ws, float* __restrict__ out)
{
    __shared__ float sm[4];
    float v = ws[threadIdx.x] + ws[threadIdx.x + 256];   // 512 partials
    #pragma unroll
    for (int off = 32; off; off >>= 1) v += __shfl_down(v, off, 64);
    const int lane = threadIdx.x & 63, wid = threadIdx.x >> 6;
    if (lane == 0) sm[wid] = v;
    __syncthreads();
    if (threadIdx.x == 0)
        out[0] = ((sm[0] + sm[1]) + (sm[2] + sm[3])) * (1.0f / 8388608.0f);
}

extern "C" void kernel_launch(void* const* d_in, const int* in_sizes, int n_in,
                              void* d_out, int out_size, void* d_ws, size_t ws_size,
                              hipStream_t stream)
{
    const float* z  = (const float*)d_in[0];   // 8388608 f32
    const float* cb = (const float*)d_in[1];   // 32768 f32
    float* out = (float*)d_out;
    float* ws  = (float*)d_ws;                 // 512 f32 partials

    vq_main<<<NBLK, 512, 0, stream>>>(z, cb, out, ws);
    vq_loss<<<1, 256, 0, stream>>>(ws, out);
}

// Round 12
// 45.845 us; speedup vs baseline: 4.9245x; 1.3340x over previous
//
#include <hip/hip_runtime.h>

// VectorQuantizer on MI355X (gfx950) — single-pass fp16 MFMA scan + exact rescore.
// Round 11: scan untouched (proven). Attack the ~40us latency stall:
//  (a) rescore parallelized 4x — the 12 candidates/pixel already live 3-per-lane
//      across the 4 lg groups; all 64 lanes reload zr (broadcast, same instr
//      count), rescore their own candidates in parallel, lexicographic (d,j)
//      shuffle-merge == np.argmin first-min exactly.
//  (b) z_q written as full 128B lines (both wave tiles together: 32 px x 2
//      planes per instr) -> kills the ~23MB split-line write amplification.

#define C_DIM   64
#define N_EMB   512
#define HW      4096
#define N_PIX   (32 * HW)            // 131072
#define ZQ_OFF  1
#define IDX_OFF (1 + N_PIX * C_DIM)
#define NBLK    512                  // 256 px per block, 2 blocks/CU

typedef _Float16 half8 __attribute__((ext_vector_type(8)));
typedef float    f32x4 __attribute__((ext_vector_type(4)));
union FragH { unsigned u[4]; half8 h8; uint4 u4; _Float16 h[8]; };

__device__ __forceinline__ unsigned umn(unsigned a, unsigned b){ return a<b?a:b; }
__device__ __forceinline__ unsigned umx(unsigned a, unsigned b){ return a>b?a:b; }

__global__ __launch_bounds__(512, 4) void vq_main(
    const float* __restrict__ z,
    const float* __restrict__ cb,
    float* __restrict__ out,
    float* __restrict__ ws)
{
    __shared__ unsigned cbh[N_EMB * 32];   // 64KB codebook as fp16 pairs (e*512), swizzled
    __shared__ float    esh5[N_EMB];       // esum + 0.5 (scan keys, positive d)
    __shared__ float    eshx[N_EMB];       // numpy-exact esum (rescore)
    __shared__ float    wsum[8];

    const int t = threadIdx.x;             // 0..511

    // ---- Stage codebook (thread t owns code row t) ----
    {
        const float* e = cb + t * C_DIM;
        float ev[64];
        #pragma unroll
        for (int q = 0; q < 16; ++q) {
            float4 v = ((const float4*)e)[q];
            ev[4*q+0]=v.x; ev[4*q+1]=v.y; ev[4*q+2]=v.z; ev[4*q+3]=v.w;
        }
        // numpy pairwise_sum(n=64): 8 accs, rounded mul, tree combine
        float r[8];
        #pragma unroll
        for (int i = 0; i < 8; ++i) r[i] = __fmul_rn(ev[i], ev[i]);
        #pragma unroll
        for (int k = 8; k < 64; k += 8) {
            #pragma unroll
            for (int i = 0; i < 8; ++i)
                r[i] = __fadd_rn(r[i], __fmul_rn(ev[k+i], ev[k+i]));
        }
        float es = __fadd_rn(
            __fadd_rn(__fadd_rn(r[0],r[1]), __fadd_rn(r[2],r[3])),
            __fadd_rn(__fadd_rn(r[4],r[5]), __fadd_rn(r[6],r[7])));
        eshx[t] = es;
        esh5[t] = es + 0.5f;
        unsigned hw_[32];
        #pragma unroll
        for (int w2 = 0; w2 < 32; ++w2) {
            union { _Float16 h[2]; unsigned u; } pk;
            pk.h[0] = (_Float16)(ev[2*w2]   * 512.0f);
            pk.h[1] = (_Float16)(ev[2*w2+1] * 512.0f);
            hw_[w2] = pk.u;
        }
        const int rs = t & 7;
        #pragma unroll
        for (int g = 0; g < 8; ++g) {
            int g2 = g ^ rs;
            *(uint4*)&cbh[t*32 + g2*4] =
                make_uint4(hw_[4*g], hw_[4*g+1], hw_[4*g+2], hw_[4*g+3]);
        }
    }
    __syncthreads();

    const int l   = t & 63;
    const int wv  = t >> 6;                // wave 0..7
    const int lg  = l >> 4;                // k-chunk / candidate group 0..3
    const int li  = l & 15;                // pixel col / code row in tile
    const int bb  = blockIdx.x >> 4;       // batch (256 px per block)
    const int g20 = (lg)     ^ (li & 7);   // swizzled granule, k-step 0
    const int g21 = (4 + lg) ^ (li & 7);   // swizzled granule, k-step 1
    const int jb  = lg * 4;
    float ls = 0.f;

    // ---- B-fragments for both pixel-tiles (wave covers 32 consecutive px) ----
    const int pxw0 = blockIdx.x * 256 + wv * 32;     // wave px base
    const float* zb0 = z + (size_t)bb * (C_DIM * HW) + ((pxw0      + li) & (HW-1));
    const float* zb1 = z + (size_t)bb * (C_DIM * HW) + ((pxw0 + 16 + li) & (HW-1));
    FragH bA0, bA1, bB0, bB1;
    {
        const float* c0 = zb0 + (size_t)(lg*8) * HW;
        const float* c1 = zb0 + (size_t)(32 + lg*8) * HW;
        const float* c2 = zb1 + (size_t)(lg*8) * HW;
        const float* c3 = zb1 + (size_t)(32 + lg*8) * HW;
        #pragma unroll
        for (int i = 0; i < 8; ++i) {
            bA0.h[i] = (_Float16)c0[(size_t)i*HW];
            bA1.h[i] = (_Float16)c1[(size_t)i*HW];
            bB0.h[i] = (_Float16)c2[(size_t)i*HW];
            bB1.h[i] = (_Float16)c3[(size_t)i*HW];
        }
    }

    // ---- MFMA scan: 32 code-tiles; per-lane top-3 keys per pixel-tile ----
    unsigned k1A=0xFFFFFFFFu,k2A=0xFFFFFFFFu,k3A=0xFFFFFFFFu;
    unsigned k1B=0xFFFFFFFFu,k2B=0xFFFFFFFFu,k3B=0xFFFFFFFFu;
    #pragma unroll 4
    for (int T = 0; T < 32; ++T) {
        const int row = T*16 + li;
        FragH a0, a1;
        a0.u4 = *(const uint4*)&cbh[row*32 + g20*4];
        a1.u4 = *(const uint4*)&cbh[row*32 + g21*4];
        f32x4 es = *(const f32x4*)&esh5[T*16 + jb];
        f32x4 accA = {0.f,0.f,0.f,0.f}, accB = {0.f,0.f,0.f,0.f};
        accA = __builtin_amdgcn_mfma_f32_16x16x32_f16(a0.h8, bA0.h8, accA, 0,0,0);
        accA = __builtin_amdgcn_mfma_f32_16x16x32_f16(a1.h8, bA1.h8, accA, 0,0,0);
        accB = __builtin_amdgcn_mfma_f32_16x16x32_f16(a0.h8, bB0.h8, accB, 0,0,0);
        accB = __builtin_amdgcn_mfma_f32_16x16x32_f16(a1.h8, bB1.h8, accB, 0,0,0);
        const int jT = T*16 + jb;
        #pragma unroll
        for (int r2 = 0; r2 < 4; ++r2) {
            float er = (r2==0)?es[0]:(r2==1)?es[1]:(r2==2)?es[2]:es[3];
            float dA = __fmaf_rn(-0.00390625f, accA[r2], er);   // >0 -> uint-sortable
            float dB = __fmaf_rn(-0.00390625f, accB[r2], er);
            unsigned keyA = (__float_as_uint(dA) & 0xFFFFFE00u) | (unsigned)(jT + r2);
            unsigned keyB = (__float_as_uint(dB) & 0xFFFFFE00u) | (unsigned)(jT + r2);
            unsigned m1,M1,m2,M2;
            m1=umn(k1A,keyA); M1=umx(k1A,keyA); k1A=m1;
            m2=umn(k2A,M1);   M2=umx(k2A,M1);   k2A=m2; k3A=umn(k3A,M2);
            m1=umn(k1B,keyB); M1=umx(k1B,keyB); k1B=m1;
            m2=umn(k2B,M1);   M2=umx(k2B,M1);   k2B=m2; k3B=umn(k3B,M2);
        }
    }

    // ---- per-pt rescore: ALL 64 lanes (candidates already 3-per-lane) ----
    int bj0 = 1023, bj1 = 1023;
    #pragma unroll
    for (int pt = 0; pt < 2; ++pt) {
        unsigned k1 = pt ? k1B : k1A, k2 = pt ? k2B : k2A, k3 = pt ? k3B : k3A;
        const float* zb = pt ? zb1 : zb0;
        const int px = pxw0 + pt*16 + li;

        // zr broadcast-reload: 16 unique addrs/instr (4-way lane broadcast)
        float zr[64];
        #pragma unroll
        for (int c = 0; c < 64; ++c) zr[c] = zb[(size_t)c * HW];
        float ap;
        {   // numpy-exact ||z||^2
            float r[8];
            #pragma unroll
            for (int i = 0; i < 8; ++i) r[i] = __fmul_rn(zr[i], zr[i]);
            #pragma unroll
            for (int k = 8; k < 64; k += 8) {
                #pragma unroll
                for (int i = 0; i < 8; ++i)
                    r[i] = __fadd_rn(r[i], __fmul_rn(zr[k+i], zr[k+i]));
            }
            ap = __fadd_rn(
                __fadd_rn(__fadd_rn(r[0],r[1]), __fadd_rn(r[2],r[3])),
                __fadd_rn(__fadd_rn(r[4],r[5]), __fadd_rn(r[6],r[7])));
        }
        // global kmin for this pixel: own 3 + cross-group min (2 shuffles)
        unsigned kmin = umn(k1, umn(k2, k3));
        kmin = umn(kmin, __shfl_xor(kmin, 16, 64));
        kmin = umn(kmin, __shfl_xor(kmin, 32, 64));
        const float thr = __uint_as_float(kmin & 0xFFFFFE00u) + 1.2e-4f;
        float bd = 3.0e38f; int bj = 1023;

        #define RESCORE(K) do {                                               \
            float da_ = __uint_as_float((K) & 0xFFFFFE00u);                   \
            if (da_ <= thr) {                                                 \
                int j_ = (int)((K) & 511u);                                   \
                const float* er_ = cb + (size_t)j_ * 64;                      \
                float a_ = 0.f;                                               \
                _Pragma("unroll")                                             \
                for (int c_ = 0; c_ < 64; ++c_)                               \
                    a_ = __fmaf_rn(zr[c_], er_[c_], a_);                      \
                float dd_ = __fsub_rn(__fadd_rn(ap, eshx[j_]),                \
                                      __fmul_rn(2.0f, a_));                   \
                if (dd_ < bd || (dd_ == bd && j_ < bj)) { bd = dd_; bj = j_; }\
            }                                                                 \
        } while (0)
        RESCORE(k1); RESCORE(k2); RESCORE(k3);
        #undef RESCORE

        // lexicographic (d, j) merge across the 4 lg groups == np first-min
        #pragma unroll
        for (int m = 16; m <= 32; m <<= 1) {
            float od = __shfl_xor(bd, m, 64);
            int   oj = __shfl_xor(bj, m, 64);
            if (od < bd || (od == bd && oj < bj)) { bd = od; bj = oj; }
        }
        if (l < 16) {                       // one lane-group writes idx + loss
            out[IDX_OFF + px] = (float)bj;
            ls += bd;                       // exact ||z - e_bj||^2 (incl. ap)
        }
        if (pt == 0) bj0 = bj; else bj1 = bj;
    }

    // ---- z_q write: both tiles together -> full 128B lines ----
    // lane l -> px pxw0 + (l&31); plane half h2 = l>>5 (planes h2*32 + cc)
    {
        const int pm = l & 31;
        const int h2 = l >> 5;
        int b0 = __shfl(bj0, pm & 15, 64);
        int b1 = __shfl(bj1, pm & 15, 64);
        const int bjw = (pm >> 4) ? b1 : b0;
        const float* eb = cb + (size_t)bjw * 64;
        float* zq = out + ZQ_OFF + (size_t)bb * (C_DIM * HW) + ((pxw0 + pm) & (HW-1));
        #pragma unroll
        for (int cc = 0; cc < 32; ++cc) {
            int c = h2 * 32 + cc;
            zq[(size_t)c * HW] = eb[c];     // 32 px x 2 planes = 2 full lines/instr
        }
    }

    // ---- loss reduce: wave -> block -> ws ----
    #pragma unroll
    for (int off = 32; off; off >>= 1) ls += __shfl_down(ls, off, 64);
    if (l == 0) wsum[wv] = ls;
    __syncthreads();
    if (t == 0) {
        float s = 0.f;
        #pragma unroll
        for (int i = 0; i < 8; ++i) s += wsum[i];
        ws[blockIdx.x] = s;
    }
}

__global__ __launch_bounds__(256) void vq_loss(
    const float* __restrict__ ws, float* __restrict__ out)
{
    __shared__ float sm[4];
    float v = ws[threadIdx.x] + ws[threadIdx.x + 256];   // 512 partials
    #pragma unroll
    for (int off = 32; off; off >>= 1) v += __shfl_down(v, off, 64);
    const int lane = threadIdx.x & 63, wid = threadIdx.x >> 6;
    if (lane == 0) sm[wid] = v;
    __syncthreads();
    if (threadIdx.x == 0)
        out[0] = ((sm[0] + sm[1]) + (sm[2] + sm[3])) * (1.0f / 8388608.0f);
}

extern "C" void kernel_launch(void* const* d_in, const int* in_sizes, int n_in,
                              void* d_out, int out_size, void* d_ws, size_t ws_size,
                              hipStream_t stream)
{
    const float* z  = (const float*)d_in[0];   // 8388608 f32
    const float* cb = (const float*)d_in[1];   // 32768 f32
    float* out = (float*)d_out;
    float* ws  = (float*)d_ws;                 // 512 f32 partials

    vq_main<<<NBLK, 512, 0, stream>>>(z, cb, out, ws);
    vq_loss<<<1, 256, 0, stream>>>(ws, out);
}

// Round 13
// 43.224 us; speedup vs baseline: 5.2231x; 1.0606x over previous
//
#include <hip/hip_runtime.h>

// VectorQuantizer on MI355X (gfx950) — single-pass fp16 MFMA scan + exact rescore.
// Round 12: rescore phase restructured from "2 sequential passes x 4-way lane
// redundancy" to "1 pass x 2-way": lanes lg0,lg1 own pixel-tile 0, lg2,lg3 own
// tile 1. Candidate handoff via shfl_xor(32) (6 shuffles), pair-merge via
// shfl_xor(16) lexicographic (d,j). Halves the zr reload (128->64 loads/thread)
// and the numpy-exact ap work, and removes one full latency chain per wave.
// Candidate set, exact arithmetic, and tie-break identical to round 11.

#define C_DIM   64
#define N_EMB   512
#define HW      4096
#define N_PIX   (32 * HW)            // 131072
#define ZQ_OFF  1
#define IDX_OFF (1 + N_PIX * C_DIM)
#define NBLK    512                  // 256 px per block, 2 blocks/CU

typedef _Float16 half8 __attribute__((ext_vector_type(8)));
typedef float    f32x4 __attribute__((ext_vector_type(4)));
union FragH { unsigned u[4]; half8 h8; uint4 u4; _Float16 h[8]; };

__device__ __forceinline__ unsigned umn(unsigned a, unsigned b){ return a<b?a:b; }
__device__ __forceinline__ unsigned umx(unsigned a, unsigned b){ return a>b?a:b; }

__global__ __launch_bounds__(512, 4) void vq_main(
    const float* __restrict__ z,
    const float* __restrict__ cb,
    float* __restrict__ out,
    float* __restrict__ ws)
{
    __shared__ unsigned cbh[N_EMB * 32];   // 64KB codebook as fp16 pairs (e*512), swizzled
    __shared__ float    esh5[N_EMB];       // esum + 0.5 (scan keys, positive d)
    __shared__ float    eshx[N_EMB];       // numpy-exact esum (rescore)
    __shared__ float    wsum[8];

    const int t = threadIdx.x;             // 0..511

    // ---- Stage codebook (thread t owns code row t) ----
    {
        const float* e = cb + t * C_DIM;
        float ev[64];
        #pragma unroll
        for (int q = 0; q < 16; ++q) {
            float4 v = ((const float4*)e)[q];
            ev[4*q+0]=v.x; ev[4*q+1]=v.y; ev[4*q+2]=v.z; ev[4*q+3]=v.w;
        }
        // numpy pairwise_sum(n=64): 8 accs, rounded mul, tree combine
        float r[8];
        #pragma unroll
        for (int i = 0; i < 8; ++i) r[i] = __fmul_rn(ev[i], ev[i]);
        #pragma unroll
        for (int k = 8; k < 64; k += 8) {
            #pragma unroll
            for (int i = 0; i < 8; ++i)
                r[i] = __fadd_rn(r[i], __fmul_rn(ev[k+i], ev[k+i]));
        }
        float es = __fadd_rn(
            __fadd_rn(__fadd_rn(r[0],r[1]), __fadd_rn(r[2],r[3])),
            __fadd_rn(__fadd_rn(r[4],r[5]), __fadd_rn(r[6],r[7])));
        eshx[t] = es;
        esh5[t] = es + 0.5f;
        unsigned hw_[32];
        #pragma unroll
        for (int w2 = 0; w2 < 32; ++w2) {
            union { _Float16 h[2]; unsigned u; } pk;
            pk.h[0] = (_Float16)(ev[2*w2]   * 512.0f);
            pk.h[1] = (_Float16)(ev[2*w2+1] * 512.0f);
            hw_[w2] = pk.u;
        }
        const int rs = t & 7;
        #pragma unroll
        for (int g = 0; g < 8; ++g) {
            int g2 = g ^ rs;
            *(uint4*)&cbh[t*32 + g2*4] =
                make_uint4(hw_[4*g], hw_[4*g+1], hw_[4*g+2], hw_[4*g+3]);
        }
    }
    __syncthreads();

    const int l   = t & 63;
    const int wv  = t >> 6;                // wave 0..7
    const int lg  = l >> 4;                // k-chunk / candidate group 0..3
    const int li  = l & 15;                // pixel col / code row in tile
    const int bb  = blockIdx.x >> 4;       // batch (256 px per block)
    const int g20 = (lg)     ^ (li & 7);   // swizzled granule, k-step 0
    const int g21 = (4 + lg) ^ (li & 7);   // swizzled granule, k-step 1
    const int jb  = lg * 4;
    float ls = 0.f;

    // ---- B-fragments for both pixel-tiles (wave covers 32 consecutive px) ----
    const int pxw0 = blockIdx.x * 256 + wv * 32;     // wave px base
    const float* zb0 = z + (size_t)bb * (C_DIM * HW) + ((pxw0      + li) & (HW-1));
    const float* zb1 = z + (size_t)bb * (C_DIM * HW) + ((pxw0 + 16 + li) & (HW-1));
    FragH bA0, bA1, bB0, bB1;
    {
        const float* c0 = zb0 + (size_t)(lg*8) * HW;
        const float* c1 = zb0 + (size_t)(32 + lg*8) * HW;
        const float* c2 = zb1 + (size_t)(lg*8) * HW;
        const float* c3 = zb1 + (size_t)(32 + lg*8) * HW;
        #pragma unroll
        for (int i = 0; i < 8; ++i) {
            bA0.h[i] = (_Float16)c0[(size_t)i*HW];
            bA1.h[i] = (_Float16)c1[(size_t)i*HW];
            bB0.h[i] = (_Float16)c2[(size_t)i*HW];
            bB1.h[i] = (_Float16)c3[(size_t)i*HW];
        }
    }

    // ---- MFMA scan: 32 code-tiles; per-lane top-3 keys per pixel-tile ----
    unsigned k1A=0xFFFFFFFFu,k2A=0xFFFFFFFFu,k3A=0xFFFFFFFFu;
    unsigned k1B=0xFFFFFFFFu,k2B=0xFFFFFFFFu,k3B=0xFFFFFFFFu;
    #pragma unroll 4
    for (int T = 0; T < 32; ++T) {
        const int row = T*16 + li;
        FragH a0, a1;
        a0.u4 = *(const uint4*)&cbh[row*32 + g20*4];
        a1.u4 = *(const uint4*)&cbh[row*32 + g21*4];
        f32x4 es = *(const f32x4*)&esh5[T*16 + jb];
        f32x4 accA = {0.f,0.f,0.f,0.f}, accB = {0.f,0.f,0.f,0.f};
        accA = __builtin_amdgcn_mfma_f32_16x16x32_f16(a0.h8, bA0.h8, accA, 0,0,0);
        accA = __builtin_amdgcn_mfma_f32_16x16x32_f16(a1.h8, bA1.h8, accA, 0,0,0);
        accB = __builtin_amdgcn_mfma_f32_16x16x32_f16(a0.h8, bB0.h8, accB, 0,0,0);
        accB = __builtin_amdgcn_mfma_f32_16x16x32_f16(a1.h8, bB1.h8, accB, 0,0,0);
        const int jT = T*16 + jb;
        #pragma unroll
        for (int r2 = 0; r2 < 4; ++r2) {
            float dA = __fmaf_rn(-0.00390625f, accA[r2], es[r2]);  // >0 -> uint-sortable
            float dB = __fmaf_rn(-0.00390625f, accB[r2], es[r2]);
            unsigned keyA = (__float_as_uint(dA) & 0xFFFFFE00u) | (unsigned)(jT + r2);
            unsigned keyB = (__float_as_uint(dB) & 0xFFFFFE00u) | (unsigned)(jT + r2);
            unsigned m1,M1,m2,M2;
            m1=umn(k1A,keyA); M1=umx(k1A,keyA); k1A=m1;
            m2=umn(k2A,M1);   M2=umx(k2A,M1);   k2A=m2; k3A=umn(k3A,M2);
            m1=umn(k1B,keyB); M1=umx(k1B,keyB); k1B=m1;
            m2=umn(k2B,M1);   M2=umx(k2B,M1);   k2B=m2; k3B=umn(k3B,M2);
        }
    }

    // ---- unified rescore: lanes lg0,lg1 own pt0's pixel li; lg2,lg3 own pt1's.
    // Candidate handoff lg0<->lg2, lg1<->lg3 via shfl_xor(32): each lane gets 6
    // of its pixel's 12 candidates; pair-merge via shfl_xor(16).
    unsigned f1 = __shfl_xor(k1A, 32, 64), f2 = __shfl_xor(k2A, 32, 64), f3 = __shfl_xor(k3A, 32, 64);
    unsigned h1 = __shfl_xor(k1B, 32, 64), h2 = __shfl_xor(k2B, 32, 64), h3 = __shfl_xor(k3B, 32, 64);
    const bool isB = (l >= 32);
    unsigned c0 = isB ? k1B : k1A, c1 = isB ? k2B : k2A, c2 = isB ? k3B : k3A;
    unsigned c3 = isB ? h1  : f1,  c4 = isB ? h2  : f2,  c5 = isB ? h3  : f3;

    const float* zb = isB ? zb1 : zb0;
    const int px = pxw0 + (isB ? 16 : 0) + li;

    // zr reload: 32 consecutive px across the wave per c-plane (full 128B lines)
    float zr[64];
    #pragma unroll
    for (int c = 0; c < 64; ++c) zr[c] = zb[(size_t)c * HW];
    float ap;
    {   // numpy-exact ||z||^2
        float r[8];
        #pragma unroll
        for (int i = 0; i < 8; ++i) r[i] = __fmul_rn(zr[i], zr[i]);
        #pragma unroll
        for (int k = 8; k < 64; k += 8) {
            #pragma unroll
            for (int i = 0; i < 8; ++i)
                r[i] = __fadd_rn(r[i], __fmul_rn(zr[k+i], zr[k+i]));
        }
        ap = __fadd_rn(
            __fadd_rn(__fadd_rn(r[0],r[1]), __fadd_rn(r[2],r[3])),
            __fadd_rn(__fadd_rn(r[4],r[5]), __fadd_rn(r[6],r[7])));
    }

    // pixel-global kmin over 12 candidates: local 6 + pair partner (xor 16)
    unsigned kmin = umn(umn(c0, c1), umn(umn(c2, c3), umn(c4, c5)));
    kmin = umn(kmin, __shfl_xor(kmin, 16, 64));
    const float thr = __uint_as_float(kmin & 0xFFFFFE00u) + 1.2e-4f;
    float bd = 3.0e38f; int bj = 1023;

    #define RESCORE(K) do {                                               \
        float da_ = __uint_as_float((K) & 0xFFFFFE00u);                   \
        if (da_ <= thr) {                                                 \
            int j_ = (int)((K) & 511u);                                   \
            const float* er_ = cb + (size_t)j_ * 64;                      \
            float a_ = 0.f;                                               \
            _Pragma("unroll")                                             \
            for (int c_ = 0; c_ < 64; ++c_)                               \
                a_ = __fmaf_rn(zr[c_], er_[c_], a_);                      \
            float dd_ = __fsub_rn(__fadd_rn(ap, eshx[j_]),                \
                                  __fmul_rn(2.0f, a_));                   \
            if (dd_ < bd || (dd_ == bd && j_ < bj)) { bd = dd_; bj = j_; }\
        }                                                                 \
    } while (0)
    RESCORE(c0); RESCORE(c1); RESCORE(c2);
    RESCORE(c3); RESCORE(c4); RESCORE(c5);
    #undef RESCORE

    // lexicographic (d, j) pair-merge == np.argmin first-min
    {
        float od = __shfl_xor(bd, 16, 64);
        int   oj = __shfl_xor(bj, 16, 64);
        if (od < bd || (od == bd && oj < bj)) { bd = od; bj = oj; }
    }
    if ((l & 16) == 0) {                   // lg0 writes pt0, lg2 writes pt1
        out[IDX_OFF + px] = (float)bj;
        ls += bd;                          // exact ||z - e_bj||^2 (incl. ap)
    }

    // ---- z_q write: both tiles together -> full 128B lines ----
    // lane l -> px pxw0 + (l&31); plane half hh = l>>5 (planes hh*32 + cc)
    {
        const int pm  = l & 31;
        const int hh  = l >> 5;
        const int src = (pm & 15) | ((pm & 16) << 1);   // owner lane of px pm
        const int bjw = __shfl(bj, src, 64);
        const float* eb = cb + (size_t)bjw * 64;
        float* zq = out + ZQ_OFF + (size_t)bb * (C_DIM * HW) + ((pxw0 + pm) & (HW-1));
        #pragma unroll
        for (int cc = 0; cc < 32; ++cc) {
            int c = hh * 32 + cc;
            zq[(size_t)c * HW] = eb[c];    // 32 px x 2 planes = 2 full lines/instr
        }
    }

    // ---- loss reduce: wave -> block -> ws ----
    #pragma unroll
    for (int off = 32; off; off >>= 1) ls += __shfl_down(ls, off, 64);
    if (l == 0) wsum[wv] = ls;
    __syncthreads();
    if (t == 0) {
        float s = 0.f;
        #pragma unroll
        for (int i = 0; i < 8; ++i) s += wsum[i];
        ws[blockIdx.x] = s;
    }
}

__global__ __launch_bounds__(256) void vq_loss(
    const float* __restrict__ ws, float* __restrict__ out)
{
    __shared__ float sm[4];
    float v = ws[threadIdx.x] + ws[threadIdx.x + 256];   // 512 partials
    #pragma unroll
    for (int off = 32; off; off >>= 1) v += __shfl_down(v, off, 64);
    const int lane = threadIdx.x & 63, wid = threadIdx.x >> 6;
    if (lane == 0) sm[wid] = v;
    __syncthreads();
    if (threadIdx.x == 0)
        out[0] = ((sm[0] + sm[1]) + (sm[2] + sm[3])) * (1.0f / 8388608.0f);
}

extern "C" void kernel_launch(void* const* d_in, const int* in_sizes, int n_in,
                              void* d_out, int out_size, void* d_ws, size_t ws_size,
                              hipStream_t stream)
{
    const float* z  = (const float*)d_in[0];   // 8388608 f32
    const float* cb = (const float*)d_in[1];   // 32768 f32
    float* out = (float*)d_out;
    float* ws  = (float*)d_ws;                 // 512 f32 partials

    vq_main<<<NBLK, 512, 0, stream>>>(z, cb, out, ws);
    vq_loss<<<1, 256, 0, stream>>>(ws, out);
}